// Round 2
// baseline (242.916 us; speedup 1.0000x reference)
//
#include <hip/hip_runtime.h>
#include <math.h>

#define IMG_H 256
#define IMG_W 256
#define NANG  180
#define NDET  363
#define NBAT  4

// One block per (angle, batch). 1024 threads = (i-quarter, column j).
// Each thread sums 64 bilinear samples; 4-way LDS reduce; detector resample.
__global__ __launch_bounds__(1024) void radon_kernel(const float* __restrict__ x,
                                                     float* __restrict__ out) {
    const int blk = blockIdx.x;
    const int a = blk >> 2;              // angle index
    const int b = blk & 3;               // batch index
    const int j  = threadIdx.x & 255;    // image column
    const int iq = threadIdx.x >> 8;     // i-quarter: 0..3

    const float* __restrict__ img = x + (size_t)b * (IMG_H * IMG_W);

    const float ang = (float)a * 0.017453292519943295f;
    const float cs = cosf(ang);
    const float sn = -sinf(ang);

    const float xcj = -1.0f + (2.0f / 255.0f) * (float)j;
    const float gx0 = xcj * cs;   // gx = gx0 - yci*sn
    const float gy0 = xcj * sn;   // gy = gy0 + yci*cs

    float sum = 0.0f;

    const int i_beg = iq * 64;
    #pragma unroll 4
    for (int ii = 0; ii < 64; ++ii) {
        const int i = i_beg + ii;
        const float yci = -1.0f + (2.0f / 255.0f) * (float)i;
        const float gx = gx0 - yci * sn;
        const float gy = gy0 + yci * cs;
        const float fx = (gx + 1.0f) * 127.5f;
        const float fy = (gy + 1.0f) * 127.5f;

        const float flx = floorf(fx);
        const float fly = floorf(fy);
        const int x0 = (int)flx;
        const int y0 = (int)fly;
        const float wx = fx - flx;
        const float wy = fy - fly;

        const bool vx0 = ((unsigned)x0 < IMG_W);
        const bool vx1 = ((unsigned)(x0 + 1) < IMG_W);
        const bool vy0 = ((unsigned)y0 < IMG_H);
        const bool vy1 = ((unsigned)(y0 + 1) < IMG_H);

        if (!((vx0 | vx1) & (vy0 | vy1))) continue;  // all 4 taps outside

        const int xc0 = min(max(x0, 0), IMG_W - 1);
        const int xc1 = min(max(x0 + 1, 0), IMG_W - 1);
        const int yc0 = min(max(y0, 0), IMG_H - 1);
        const int yc1 = min(max(y0 + 1, 0), IMG_H - 1);

        const float* r0 = img + yc0 * IMG_W;
        const float* r1 = img + yc1 * IMG_W;

        const float v00 = (vy0 && vx0) ? r0[xc0] : 0.0f;
        const float v01 = (vy0 && vx1) ? r0[xc1] : 0.0f;
        const float v10 = (vy1 && vx0) ? r1[xc0] : 0.0f;
        const float v11 = (vy1 && vx1) ? r1[xc1] : 0.0f;

        sum += (1.0f - wy) * ((1.0f - wx) * v00 + wx * v01)
             +         wy  * ((1.0f - wx) * v10 + wx * v11);
    }

    __shared__ float partial[4][IMG_W];
    partial[iq][j] = sum;
    __syncthreads();

    // reduce 4 quarters -> partial[0][j]
    if (threadIdx.x < IMG_W) {
        partial[0][j] = partial[0][j] + partial[1][j] + partial[2][j] + partial[3][j];
    }
    __syncthreads();

    // detector resample: pos = d * 255/362, linear interp of proj
    if (threadIdx.x < NDET) {
        const int d = threadIdx.x;
        const float pos = (float)d * (255.0f / 362.0f);
        const float fp = floorf(pos);
        const int p0 = (int)fp;
        const int p1 = min(p0 + 1, IMG_W - 1);
        const float w = pos - fp;
        const float val = partial[0][p0] * (1.0f - w) + partial[0][p1] * w;
        out[(size_t)b * (NANG * NDET) + a * NDET + d] = val;
    }
}

extern "C" void kernel_launch(void* const* d_in, const int* in_sizes, int n_in,
                              void* d_out, int out_size, void* d_ws, size_t ws_size,
                              hipStream_t stream) {
    const float* x = (const float*)d_in[0];
    float* out = (float*)d_out;
    (void)in_sizes; (void)n_in; (void)out_size; (void)d_ws; (void)ws_size;
    radon_kernel<<<dim3(NANG * NBAT), dim3(1024), 0, stream>>>(x, out);
}

// Round 3
// 77.249 us; speedup vs baseline: 3.1446x; 3.1446x over previous
//
#include <hip/hip_runtime.h>
#include <math.h>

#define IMG   256
#define NANG  180
#define NDET  363
#define NBAT  4
#define PAD   3
#define PS    264                 // padded stride (floats), 256 + 2*PAD + 2 slop
#define PSZ   (PS * PS)           // floats per padded image
#define WS_FLOATS (8 * PSZ)       // 4 normal + 4 transposed
#define WS_BYTES  (WS_FLOATS * 4)

// ---- prep: build zero-padded normal + transposed copies in ws ----
__global__ __launch_bounds__(1024) void prep_kernel(const float* __restrict__ x,
                                                    float* __restrict__ ws) {
    __shared__ float tile[32][33];
    const int b = blockIdx.z;
    const int x0 = blockIdx.x * 32, y0 = blockIdx.y * 32;
    const int tx = threadIdx.x, ty = threadIdx.y;

    const float v = x[(size_t)b * (IMG * IMG) + (y0 + ty) * IMG + (x0 + tx)];
    tile[ty][tx] = v;
    // normal padded copy: N[(y+PAD)*PS + x+PAD] = img[y][x]
    ws[(size_t)b * PSZ + (y0 + ty + PAD) * PS + (x0 + tx + PAD)] = v;
    __syncthreads();
    // transposed padded copy: T[(x+PAD)*PS + y+PAD] = img[y][x], coalesced in y
    ws[(size_t)(4 + b) * PSZ + (x0 + ty + PAD) * PS + (y0 + tx + PAD)] = tile[tx][ty];
}

// ---- main: one block per (angle,batch); thread = column j ----
__global__ __launch_bounds__(256) void radon_main(const float* __restrict__ ws,
                                                  float* __restrict__ out) {
    const int blk = blockIdx.x;
    const int a = blk >> 2;
    const int b = blk & 3;
    const int j = threadIdx.x;

    const float ang = (float)a * 0.017453292519943295f;
    const float cs = cosf(ang);        // cos_t = cos(-ang)
    const float sn = -sinf(ang);       // sin_t = sin(-ang)

    const float xcj = -1.0f + (2.0f / 255.0f) * (float)j;
    // fx(i) = 127.5*(xcj*cs + sn + 1) + i*(-sn);  fy(i) = 127.5*(xcj*sn - cs + 1) + i*cs
    const float fx0 = 127.5f * (xcj * cs + sn + 1.0f);
    const float dfx = -sn;
    const float fy0 = 127.5f * (xcj * sn - cs + 1.0f);
    const float dfy = cs;

    // choose layout so the lane-fast coordinate is the stored row direction
    const bool swp = fabsf(sn) > fabsf(cs);
    const float rc0 = swp ? fx0 : fy0;  const float drow = swp ? dfx : dfy;
    const float cc0 = swp ? fy0 : fx0;  const float dcol = swp ? dfy : dfx;
    const float* __restrict__ base = ws + (size_t)(swp ? 4 + b : b) * PSZ;

    // valid i-window: both coords in ~[-1,256]; conservative, slop lands in pad
    float lo = 0.0f, hi = 255.0f;
    {
        if (fabsf(drow) > 1e-5f) {
            const float t1 = (-1.5f - rc0) / drow, t2 = (256.5f - rc0) / drow;
            lo = fmaxf(lo, fminf(t1, t2));
            hi = fminf(hi, fmaxf(t1, t2));
        } else if (rc0 < -1.5f || rc0 > 256.5f) { lo = 1.0f; hi = 0.0f; }
        if (fabsf(dcol) > 1e-5f) {
            const float t1 = (-1.5f - cc0) / dcol, t2 = (256.5f - cc0) / dcol;
            lo = fmaxf(lo, fminf(t1, t2));
            hi = fminf(hi, fmaxf(t1, t2));
        } else if (cc0 < -1.5f || cc0 > 256.5f) { lo = 1.0f; hi = 0.0f; }
    }
    const int ilo = max(0, (int)floorf(lo));
    const int ihi = min(255, (int)ceilf(hi));

    float sum = 0.0f;
    #pragma unroll 4
    for (int i = ilo; i <= ihi; ++i) {
        const float rc = fmaf((float)i, drow, rc0);
        const float cc = fmaf((float)i, dcol, cc0);
        const float rf = floorf(rc);
        const float cf = floorf(cc);
        const int r0 = (int)rf;
        const int c0 = (int)cf;
        const float wr = rc - rf;
        const float wc = cc - cf;

        const float* p = base + (r0 + PAD) * PS + (c0 + PAD);
        const float v00 = p[0], v01 = p[1];
        const float v10 = p[PS], v11 = p[PS + 1];
        const float top = v00 + wc * (v01 - v00);
        const float bot = v10 + wc * (v11 - v10);
        sum += top + wr * (bot - top);
    }

    __shared__ float proj[IMG];
    proj[j] = sum;
    __syncthreads();

    for (int d = j; d < NDET; d += 256) {
        const float pos = (float)d * (255.0f / 362.0f);
        const float fp = floorf(pos);
        const int p0 = (int)fp;
        const int p1 = min(p0 + 1, IMG - 1);
        const float w = pos - fp;
        out[(size_t)b * (NANG * NDET) + a * NDET + d] = proj[p0] * (1.0f - w) + proj[p1] * w;
    }
}

// ---- fallback (round-1 kernel, used only if ws is too small) ----
__global__ __launch_bounds__(256) void radon_fallback(const float* __restrict__ x,
                                                      float* __restrict__ out) {
    const int blk = blockIdx.x;
    const int a = blk >> 2;
    const int b = blk & 3;
    const int j = threadIdx.x;
    const float* __restrict__ img = x + (size_t)b * (IMG * IMG);
    const float ang = (float)a * 0.017453292519943295f;
    const float cs = cosf(ang);
    const float sn = -sinf(ang);
    const float xcj = -1.0f + (2.0f / 255.0f) * (float)j;
    const float gx0 = xcj * cs;
    const float gy0 = xcj * sn;
    float sum = 0.0f;
    for (int i = 0; i < IMG; ++i) {
        const float yci = -1.0f + (2.0f / 255.0f) * (float)i;
        const float fx = (gx0 - yci * sn + 1.0f) * 127.5f;
        const float fy = (gy0 + yci * cs + 1.0f) * 127.5f;
        const float flx = floorf(fx), fly = floorf(fy);
        const int x0 = (int)flx, y0 = (int)fly;
        const float wx = fx - flx, wy = fy - fly;
        const bool vx0 = ((unsigned)x0 < IMG), vx1 = ((unsigned)(x0 + 1) < IMG);
        const bool vy0 = ((unsigned)y0 < IMG), vy1 = ((unsigned)(y0 + 1) < IMG);
        if (!((vx0 | vx1) & (vy0 | vy1))) continue;
        const int xc0 = min(max(x0, 0), IMG - 1), xc1 = min(max(x0 + 1, 0), IMG - 1);
        const int yc0 = min(max(y0, 0), IMG - 1), yc1 = min(max(y0 + 1, 0), IMG - 1);
        const float* r0 = img + yc0 * IMG;
        const float* r1 = img + yc1 * IMG;
        const float v00 = (vy0 && vx0) ? r0[xc0] : 0.0f;
        const float v01 = (vy0 && vx1) ? r0[xc1] : 0.0f;
        const float v10 = (vy1 && vx0) ? r1[xc0] : 0.0f;
        const float v11 = (vy1 && vx1) ? r1[xc1] : 0.0f;
        sum += (1.0f - wy) * ((1.0f - wx) * v00 + wx * v01)
             +         wy  * ((1.0f - wx) * v10 + wx * v11);
    }
    __shared__ float proj[IMG];
    proj[j] = sum;
    __syncthreads();
    for (int d = j; d < NDET; d += 256) {
        const float pos = (float)d * (255.0f / 362.0f);
        const float fp = floorf(pos);
        const int p0 = (int)fp;
        const int p1 = min(p0 + 1, IMG - 1);
        const float w = pos - fp;
        out[(size_t)b * (NANG * NDET) + a * NDET + d] = proj[p0] * (1.0f - w) + proj[p1] * w;
    }
}

extern "C" void kernel_launch(void* const* d_in, const int* in_sizes, int n_in,
                              void* d_out, int out_size, void* d_ws, size_t ws_size,
                              hipStream_t stream) {
    const float* x = (const float*)d_in[0];
    float* out = (float*)d_out;
    (void)in_sizes; (void)n_in; (void)out_size;

    if (ws_size >= (size_t)WS_BYTES) {
        float* ws = (float*)d_ws;
        hipMemsetAsync(ws, 0, WS_BYTES, stream);
        prep_kernel<<<dim3(8, 8, 4), dim3(32, 32), 0, stream>>>(x, ws);
        radon_main<<<dim3(NANG * NBAT), dim3(256), 0, stream>>>(ws, out);
    } else {
        radon_fallback<<<dim3(NANG * NBAT), dim3(256), 0, stream>>>(x, out);
    }
}

// Round 4
// 69.883 us; speedup vs baseline: 3.4760x; 1.1054x over previous
//
#include <hip/hip_runtime.h>
#include <math.h>

#define IMG   256
#define NANG  180
#define NDET  363
#define NBAT  4
#define PAD   3
#define PS    264                    // padded stride (texels)
#define PSZ   (PS * PS)              // texels per layout
#define PP_OFF (2 * PSZ)             // proj_part offset (in float4s) inside ws
#define WS_F4  (2 * PSZ + NANG * 2 * IMG)
#define WS_NEED ((size_t)WS_F4 * 16)

__device__ __forceinline__ float4 lerp4(const float4 lo, const float4 hi, const float w) {
    float4 r;
    r.x = fmaf(w, hi.x - lo.x, lo.x);
    r.y = fmaf(w, hi.y - lo.y, lo.y);
    r.z = fmaf(w, hi.z - lo.z, lo.z);
    r.w = fmaf(w, hi.w - lo.w, lo.w);
    return r;
}

// ---- prep: batch-interleaved zero-padded normal + transposed layouts ----
__global__ __launch_bounds__(1024) void prep_kernel(const float* __restrict__ x,
                                                    float4* __restrict__ ws) {
    __shared__ float4 tile[32][33];
    const int tx = threadIdx.x, ty = threadIdx.y;
    const int px = blockIdx.x * 32 + tx;   // padded x
    const int py = blockIdx.y * 32 + ty;   // padded y
    const int ix = px - PAD, iy = py - PAD;

    float4 v = make_float4(0.f, 0.f, 0.f, 0.f);
    if ((unsigned)ix < IMG && (unsigned)iy < IMG) {
        const size_t o = (size_t)iy * IMG + ix;
        v.x = x[o];
        v.y = x[o + IMG * IMG];
        v.z = x[o + 2 * IMG * IMG];
        v.w = x[o + 3 * IMG * IMG];
    }
    if (px < PS && py < PS) ws[(size_t)py * PS + px] = v;       // N4[py][px]
    tile[ty][tx] = v;
    __syncthreads();
    const int opx = blockIdx.y * 32 + tx;  // fast dim = original py
    const int opy = blockIdx.x * 32 + ty;  // slow dim = original px
    if (opx < PS && opy < PS)
        ws[(size_t)PSZ + (size_t)opy * PS + opx] = tile[tx][ty]; // T4[u][v]=img[v][u]
}

// ---- main: block = (angle, i-half); 512 threads = (i-quarter-of-half, j) ----
__global__ __launch_bounds__(512) void radon_main(const float4* __restrict__ ws,
                                                  float4* __restrict__ proj_part) {
    const int a  = blockIdx.x;
    const int h  = blockIdx.y;
    const int j  = threadIdx.x & 255;
    const int iq = threadIdx.x >> 8;       // 0..1

    const float ang = (float)a * 0.017453292519943295f;
    const float cs = cosf(ang);            // cos(-ang)
    const float sn = -sinf(ang);           // sin(-ang)

    const float xcj = -1.0f + (2.0f / 255.0f) * (float)j;
    const float fx0 = 127.5f * (xcj * cs + sn + 1.0f);
    const float dfx = -sn;
    const float fy0 = 127.5f * (xcj * sn - cs + 1.0f);
    const float dfy = cs;

    // layout so lane-fast coordinate is the stored-row (contiguous) direction
    const bool swp = fabsf(sn) > fabsf(cs);
    const float rc0 = swp ? fx0 : fy0;  const float drow = swp ? dfx : dfy;
    const float cc0 = swp ? fy0 : fx0;  const float dcol = swp ? dfy : dfx;
    const float4* __restrict__ base = ws + (swp ? PSZ : 0);

    // valid i-window (conservative; slop lands in the zero pad)
    float lo = 0.0f, hi = 255.0f;
    if (fabsf(drow) > 1e-5f) {
        const float t1 = (-1.5f - rc0) / drow, t2 = (256.5f - rc0) / drow;
        lo = fmaxf(lo, fminf(t1, t2));
        hi = fminf(hi, fmaxf(t1, t2));
    } else if (rc0 < -1.5f || rc0 > 256.5f) { lo = 1.0f; hi = 0.0f; }
    if (fabsf(dcol) > 1e-5f) {
        const float t1 = (-1.5f - cc0) / dcol, t2 = (256.5f - cc0) / dcol;
        lo = fmaxf(lo, fminf(t1, t2));
        hi = fminf(hi, fmaxf(t1, t2));
    } else if (cc0 < -1.5f || cc0 > 256.5f) { lo = 1.0f; hi = 0.0f; }

    const int tlo = h * 128 + iq * 64;
    const int ilo = max(max(0,   (int)floorf(lo)), tlo);
    const int ihi = min(min(255, (int)ceilf(hi)), tlo + 63);

    float4 sum = make_float4(0.f, 0.f, 0.f, 0.f);
    #pragma unroll 4
    for (int i = ilo; i <= ihi; ++i) {
        const float rc = fmaf((float)i, drow, rc0);
        const float cc = fmaf((float)i, dcol, cc0);
        const float rf = floorf(rc);
        const float cf = floorf(cc);
        const float wr = rc - rf;
        const float wc = cc - cf;
        // integer texel index via exact float fma: rf*PS + cf fits in 2^24
        const int idx = (int)fmaf(rf, (float)PS, cf) + (PAD * PS + PAD);
        const float4* p = base + idx;
        const float4 v00 = p[0],  v01 = p[1];
        const float4 v10 = p[PS], v11 = p[PS + 1];
        const float4 top = lerp4(v00, v01, wc);
        const float4 bot = lerp4(v10, v11, wc);
        sum.x += fmaf(wr, bot.x - top.x, top.x);
        sum.y += fmaf(wr, bot.y - top.y, top.y);
        sum.z += fmaf(wr, bot.z - top.z, top.z);
        sum.w += fmaf(wr, bot.w - top.w, top.w);
    }

    __shared__ float4 part[2][IMG];
    part[iq][j] = sum;
    __syncthreads();
    if (iq == 0) {
        const float4 o = part[1][j];
        float4 s = part[0][j];
        s.x += o.x; s.y += o.y; s.z += o.z; s.w += o.w;
        proj_part[(size_t)(a * 2 + h) * IMG + j] = s;
    }
}

// ---- detect: per angle, sum halves, resample 363 detectors, write 4 batches ----
__global__ __launch_bounds__(384) void detect_kernel(const float4* __restrict__ proj_part,
                                                     float* __restrict__ out) {
    const int a = blockIdx.x;
    const int t = threadIdx.x;
    __shared__ float4 proj[IMG];
    if (t < IMG) {
        const float4 p0 = proj_part[(size_t)(a * 2 + 0) * IMG + t];
        const float4 p1 = proj_part[(size_t)(a * 2 + 1) * IMG + t];
        proj[t] = make_float4(p0.x + p1.x, p0.y + p1.y, p0.z + p1.z, p0.w + p1.w);
    }
    __syncthreads();
    if (t < NDET) {
        const float pos = (float)t * (255.0f / 362.0f);
        const float fp = floorf(pos);
        const int p0 = (int)fp;
        const int p1 = min(p0 + 1, IMG - 1);
        const float w = pos - fp;
        const float4 lo = proj[p0], hi = proj[p1];
        const size_t o = (size_t)a * NDET + t;
        out[o]                      = fmaf(w, hi.x - lo.x, lo.x);
        out[o + 1 * NANG * NDET]    = fmaf(w, hi.y - lo.y, lo.y);
        out[o + 2 * NANG * NDET]    = fmaf(w, hi.z - lo.z, lo.z);
        out[o + 3 * NANG * NDET]    = fmaf(w, hi.w - lo.w, lo.w);
    }
}

// ---- fallback (round-1 kernel) if ws is too small ----
__global__ __launch_bounds__(256) void radon_fallback(const float* __restrict__ x,
                                                      float* __restrict__ out) {
    const int blk = blockIdx.x;
    const int a = blk >> 2;
    const int b = blk & 3;
    const int j = threadIdx.x;
    const float* __restrict__ img = x + (size_t)b * (IMG * IMG);
    const float ang = (float)a * 0.017453292519943295f;
    const float cs = cosf(ang);
    const float sn = -sinf(ang);
    const float xcj = -1.0f + (2.0f / 255.0f) * (float)j;
    const float gx0 = xcj * cs;
    const float gy0 = xcj * sn;
    float sum = 0.0f;
    for (int i = 0; i < IMG; ++i) {
        const float yci = -1.0f + (2.0f / 255.0f) * (float)i;
        const float fx = (gx0 - yci * sn + 1.0f) * 127.5f;
        const float fy = (gy0 + yci * cs + 1.0f) * 127.5f;
        const float flx = floorf(fx), fly = floorf(fy);
        const int x0 = (int)flx, y0 = (int)fly;
        const float wx = fx - flx, wy = fy - fly;
        const bool vx0 = ((unsigned)x0 < IMG), vx1 = ((unsigned)(x0 + 1) < IMG);
        const bool vy0 = ((unsigned)y0 < IMG), vy1 = ((unsigned)(y0 + 1) < IMG);
        if (!((vx0 | vx1) & (vy0 | vy1))) continue;
        const int xc0 = min(max(x0, 0), IMG - 1), xc1 = min(max(x0 + 1, 0), IMG - 1);
        const int yc0 = min(max(y0, 0), IMG - 1), yc1 = min(max(y0 + 1, 0), IMG - 1);
        const float* r0 = img + yc0 * IMG;
        const float* r1 = img + yc1 * IMG;
        const float v00 = (vy0 && vx0) ? r0[xc0] : 0.0f;
        const float v01 = (vy0 && vx1) ? r0[xc1] : 0.0f;
        const float v10 = (vy1 && vx0) ? r1[xc0] : 0.0f;
        const float v11 = (vy1 && vx1) ? r1[xc1] : 0.0f;
        sum += (1.0f - wy) * ((1.0f - wx) * v00 + wx * v01)
             +         wy  * ((1.0f - wx) * v10 + wx * v11);
    }
    __shared__ float proj[IMG];
    proj[j] = sum;
    __syncthreads();
    for (int d = j; d < NDET; d += 256) {
        const float pos = (float)d * (255.0f / 362.0f);
        const float fp = floorf(pos);
        const int p0 = (int)fp;
        const int p1 = min(p0 + 1, IMG - 1);
        const float w = pos - fp;
        out[(size_t)b * (NANG * NDET) + a * NDET + d] = proj[p0] * (1.0f - w) + proj[p1] * w;
    }
}

extern "C" void kernel_launch(void* const* d_in, const int* in_sizes, int n_in,
                              void* d_out, int out_size, void* d_ws, size_t ws_size,
                              hipStream_t stream) {
    const float* x = (const float*)d_in[0];
    float* out = (float*)d_out;
    (void)in_sizes; (void)n_in; (void)out_size;

    if (ws_size >= WS_NEED) {
        float4* ws = (float4*)d_ws;
        prep_kernel<<<dim3(9, 9), dim3(32, 32), 0, stream>>>(x, ws);
        radon_main<<<dim3(NANG, 2), dim3(512), 0, stream>>>(ws, ws + PP_OFF);
        detect_kernel<<<dim3(NANG), dim3(384), 0, stream>>>(ws + PP_OFF, out);
    } else {
        radon_fallback<<<dim3(NANG * NBAT), dim3(256), 0, stream>>>(x, out);
    }
}

// Round 5
// 32.976 us; speedup vs baseline: 7.3665x; 2.1192x over previous
//
#include <hip/hip_runtime.h>
#include <hip/hip_fp16.h>
#include <math.h>

#define IMG   256
#define NANG  180
#define NDET  363
#define PAD   3
#define PS    264                    // padded stride (texels)
#define PSZ   (PS * PS)              // texels per layout
#define TEX_BYTES ((size_t)2 * PSZ * 8)          // 2 layouts of uint2 texels
#define PP_BYTES  ((size_t)NANG * 4 * IMG * 16)  // proj_part float4
#define WS_NEED   (TEX_BYTES + PP_BYTES)

__device__ __forceinline__ __half2 u2h2(unsigned u) {
    return *reinterpret_cast<__half2*>(&u);
}
__device__ __forceinline__ unsigned h22u(__half2 h) {
    return *reinterpret_cast<unsigned*>(&h);
}

// ---- prep: fp16x4 batch-interleaved zero-padded normal + transposed layouts ----
__global__ __launch_bounds__(1024) void prep_kernel(const float* __restrict__ x,
                                                    uint2* __restrict__ ws) {
    __shared__ uint2 tile[32][33];
    const int tx = threadIdx.x, ty = threadIdx.y;
    const int px = blockIdx.x * 32 + tx;   // padded x
    const int py = blockIdx.y * 32 + ty;   // padded y
    const int ix = px - PAD, iy = py - PAD;

    uint2 t = make_uint2(0u, 0u);
    if ((unsigned)ix < IMG && (unsigned)iy < IMG) {
        const size_t o = (size_t)iy * IMG + ix;
        const __half2 lo = __floats2half2_rn(x[o],                 x[o + IMG * IMG]);
        const __half2 hi = __floats2half2_rn(x[o + 2 * IMG * IMG], x[o + 3 * IMG * IMG]);
        t.x = h22u(lo);
        t.y = h22u(hi);
    }
    if (px < PS && py < PS) ws[(size_t)py * PS + px] = t;          // N[py][px]
    tile[ty][tx] = t;
    __syncthreads();
    const int opx = blockIdx.y * 32 + tx;  // fast dim = original py
    const int opy = blockIdx.x * 32 + ty;  // slow dim = original px
    if (opx < PS && opy < PS)
        ws[(size_t)PSZ + (size_t)opy * PS + opx] = tile[tx][ty];   // T[u][v]=img[v][u]
}

// ---- main: block = (angle, i-quarter); 512 threads = (i-eighth, j) ----
__global__ __launch_bounds__(512) void radon_main(const uint2* __restrict__ ws,
                                                  float4* __restrict__ proj_part) {
    const int a  = blockIdx.x;
    const int q  = blockIdx.y;             // i-quarter 0..3
    const int j  = threadIdx.x & 255;
    const int iq = threadIdx.x >> 8;       // 0..1 eighth-within-quarter

    const float ang = (float)a * 0.017453292519943295f;
    const float cs = cosf(ang);            // cos(-ang)
    const float sn = -sinf(ang);           // sin(-ang)

    const float xcj = -1.0f + (2.0f / 255.0f) * (float)j;
    const float fx0 = 127.5f * (xcj * cs + sn + 1.0f);
    const float dfx = -sn;
    const float fy0 = 127.5f * (xcj * sn - cs + 1.0f);
    const float dfy = cs;

    // layout so the lane-fast coordinate is the stored-row (contiguous) direction
    const bool swp = fabsf(sn) > fabsf(cs);
    const float rc0 = swp ? fx0 : fy0;  const float drow = swp ? dfx : dfy;
    const float cc0 = swp ? fy0 : fx0;  const float dcol = swp ? dfy : dfx;
    const uint2* __restrict__ base = ws + (swp ? PSZ : 0);

    // valid i-window (conservative; slop lands in the zero pad)
    float lo = 0.0f, hi = 255.0f;
    if (fabsf(drow) > 1e-5f) {
        const float t1 = (-1.5f - rc0) / drow, t2 = (256.5f - rc0) / drow;
        lo = fmaxf(lo, fminf(t1, t2));
        hi = fminf(hi, fmaxf(t1, t2));
    } else if (rc0 < -1.5f || rc0 > 256.5f) { lo = 1.0f; hi = 0.0f; }
    if (fabsf(dcol) > 1e-5f) {
        const float t1 = (-1.5f - cc0) / dcol, t2 = (256.5f - cc0) / dcol;
        lo = fmaxf(lo, fminf(t1, t2));
        hi = fminf(hi, fmaxf(t1, t2));
    } else if (cc0 < -1.5f || cc0 > 256.5f) { lo = 1.0f; hi = 0.0f; }

    const int tlo = q * 64 + iq * 32;
    const int ilo = max(max(0,   (int)floorf(lo)), tlo);
    const int ihi = min(min(255, (int)ceilf(hi)), tlo + 31);

    float4 sum = make_float4(0.f, 0.f, 0.f, 0.f);
    #pragma unroll 4
    for (int i = ilo; i <= ihi; ++i) {
        const float rc = fmaf((float)i, drow, rc0);
        const float cc = fmaf((float)i, dcol, cc0);
        const float rf = floorf(rc);
        const float cf = floorf(cc);
        const float wr = rc - rf;
        const float wc = cc - cf;
        const int idx = (int)fmaf(rf, (float)PS, cf) + (PAD * PS + PAD);

        // one 16B load = both horizontal taps (4 batches each), per row
        const uint4 tr = *reinterpret_cast<const uint4*>(base + idx);
        const uint4 br = *reinterpret_cast<const uint4*>(base + idx + PS);

        const __half2 wc2 = __float2half2_rn(wc);
        const __half2 wr2 = __float2half2_rn(wr);

        const __half2 v00a = u2h2(tr.x), v00b = u2h2(tr.y);
        const __half2 v01a = u2h2(tr.z), v01b = u2h2(tr.w);
        const __half2 v10a = u2h2(br.x), v10b = u2h2(br.y);
        const __half2 v11a = u2h2(br.z), v11b = u2h2(br.w);

        const __half2 topa = __hfma2(wc2, __hsub2(v01a, v00a), v00a);
        const __half2 topb = __hfma2(wc2, __hsub2(v01b, v00b), v00b);
        const __half2 bota = __hfma2(wc2, __hsub2(v11a, v10a), v10a);
        const __half2 botb = __hfma2(wc2, __hsub2(v11b, v10b), v10b);
        const __half2 ra = __hfma2(wr2, __hsub2(bota, topa), topa);
        const __half2 rb = __hfma2(wr2, __hsub2(botb, topb), topb);

        sum.x += __low2float(ra);
        sum.y += __high2float(ra);
        sum.z += __low2float(rb);
        sum.w += __high2float(rb);
    }

    __shared__ float4 part[2][IMG];
    part[iq][j] = sum;
    __syncthreads();
    if (iq == 0) {
        const float4 o = part[1][j];
        float4 s = part[0][j];
        s.x += o.x; s.y += o.y; s.z += o.z; s.w += o.w;
        proj_part[(size_t)(a * 4 + q) * IMG + j] = s;
    }
}

// ---- detect: per angle, sum quarters, resample detectors, write 4 batches ----
__global__ __launch_bounds__(384) void detect_kernel(const float4* __restrict__ proj_part,
                                                     float* __restrict__ out) {
    const int a = blockIdx.x;
    const int t = threadIdx.x;
    __shared__ float4 proj[IMG];
    if (t < IMG) {
        float4 s = proj_part[(size_t)(a * 4 + 0) * IMG + t];
        #pragma unroll
        for (int qq = 1; qq < 4; ++qq) {
            const float4 p = proj_part[(size_t)(a * 4 + qq) * IMG + t];
            s.x += p.x; s.y += p.y; s.z += p.z; s.w += p.w;
        }
        proj[t] = s;
    }
    __syncthreads();
    if (t < NDET) {
        const float pos = (float)t * (255.0f / 362.0f);
        const float fp = floorf(pos);
        const int p0 = (int)fp;
        const int p1 = min(p0 + 1, IMG - 1);
        const float w = pos - fp;
        const float4 lo = proj[p0], hi = proj[p1];
        const size_t o = (size_t)a * NDET + t;
        out[o]                   = fmaf(w, hi.x - lo.x, lo.x);
        out[o + 1 * NANG * NDET] = fmaf(w, hi.y - lo.y, lo.y);
        out[o + 2 * NANG * NDET] = fmaf(w, hi.z - lo.z, lo.z);
        out[o + 3 * NANG * NDET] = fmaf(w, hi.w - lo.w, lo.w);
    }
}

// ---- fallback (round-1 kernel) if ws is too small ----
__global__ __launch_bounds__(256) void radon_fallback(const float* __restrict__ x,
                                                      float* __restrict__ out) {
    const int blk = blockIdx.x;
    const int a = blk >> 2;
    const int b = blk & 3;
    const int j = threadIdx.x;
    const float* __restrict__ img = x + (size_t)b * (IMG * IMG);
    const float ang = (float)a * 0.017453292519943295f;
    const float cs = cosf(ang);
    const float sn = -sinf(ang);
    const float xcj = -1.0f + (2.0f / 255.0f) * (float)j;
    const float gx0 = xcj * cs;
    const float gy0 = xcj * sn;
    float sum = 0.0f;
    for (int i = 0; i < IMG; ++i) {
        const float yci = -1.0f + (2.0f / 255.0f) * (float)i;
        const float fx = (gx0 - yci * sn + 1.0f) * 127.5f;
        const float fy = (gy0 + yci * cs + 1.0f) * 127.5f;
        const float flx = floorf(fx), fly = floorf(fy);
        const int x0 = (int)flx, y0 = (int)fly;
        const float wx = fx - flx, wy = fy - fly;
        const bool vx0 = ((unsigned)x0 < IMG), vx1 = ((unsigned)(x0 + 1) < IMG);
        const bool vy0 = ((unsigned)y0 < IMG), vy1 = ((unsigned)(y0 + 1) < IMG);
        if (!((vx0 | vx1) & (vy0 | vy1))) continue;
        const int xc0 = min(max(x0, 0), IMG - 1), xc1 = min(max(x0 + 1, 0), IMG - 1);
        const int yc0 = min(max(y0, 0), IMG - 1), yc1 = min(max(y0 + 1, 0), IMG - 1);
        const float* r0 = img + yc0 * IMG;
        const float* r1 = img + yc1 * IMG;
        const float v00 = (vy0 && vx0) ? r0[xc0] : 0.0f;
        const float v01 = (vy0 && vx1) ? r0[xc1] : 0.0f;
        const float v10 = (vy1 && vx0) ? r1[xc0] : 0.0f;
        const float v11 = (vy1 && vx1) ? r1[xc1] : 0.0f;
        sum += (1.0f - wy) * ((1.0f - wx) * v00 + wx * v01)
             +         wy  * ((1.0f - wx) * v10 + wx * v11);
    }
    __shared__ float proj[IMG];
    proj[j] = sum;
    __syncthreads();
    for (int d = j; d < NDET; d += 256) {
        const float pos = (float)d * (255.0f / 362.0f);
        const float fp = floorf(pos);
        const int p0 = (int)fp;
        const int p1 = min(p0 + 1, IMG - 1);
        const float w = pos - fp;
        out[(size_t)b * (NANG * NDET) + a * NDET + d] = proj[p0] * (1.0f - w) + proj[p1] * w;
    }
}

extern "C" void kernel_launch(void* const* d_in, const int* in_sizes, int n_in,
                              void* d_out, int out_size, void* d_ws, size_t ws_size,
                              hipStream_t stream) {
    const float* x = (const float*)d_in[0];
    float* out = (float*)d_out;
    (void)in_sizes; (void)n_in; (void)out_size;

    if (ws_size >= WS_NEED) {
        uint2* tex = (uint2*)d_ws;
        float4* proj_part = (float4*)((char*)d_ws + TEX_BYTES);
        prep_kernel<<<dim3(9, 9), dim3(32, 32), 0, stream>>>(x, tex);
        radon_main<<<dim3(NANG, 4), dim3(512), 0, stream>>>(tex, proj_part);
        detect_kernel<<<dim3(NANG), dim3(384), 0, stream>>>(proj_part, out);
    } else {
        radon_fallback<<<dim3(NANG * 4), dim3(256), 0, stream>>>(x, out);
    }
}

// Round 6
// 31.425 us; speedup vs baseline: 7.7301x; 1.0494x over previous
//
#include <hip/hip_runtime.h>
#include <hip/hip_fp16.h>
#include <math.h>

#define IMG   256
#define NANG  180
#define NDET  363
#define PAD   3
#define PS    264                    // padded stride (texels)
#define PSZ   (PS * PS)              // texels per layout
#define TEX_BYTES ((size_t)2 * PSZ * 8)          // 2 layouts of uint2 texels
#define PP_BYTES  ((size_t)NANG * 2 * IMG * 16)  // proj_part float4 (2 i-halves)
#define WS_NEED   (TEX_BYTES + PP_BYTES)

__device__ __forceinline__ __half2 u2h2(unsigned u) {
    return *reinterpret_cast<__half2*>(&u);
}
__device__ __forceinline__ unsigned h22u(__half2 h) {
    return *reinterpret_cast<unsigned*>(&h);
}

// ---- prep: fp16x4 batch-interleaved zero-padded normal + transposed layouts ----
__global__ __launch_bounds__(1024) void prep_kernel(const float* __restrict__ x,
                                                    uint2* __restrict__ ws) {
    __shared__ uint2 tile[32][33];
    const int tx = threadIdx.x, ty = threadIdx.y;
    const int px = blockIdx.x * 32 + tx;   // padded x
    const int py = blockIdx.y * 32 + ty;   // padded y
    const int ix = px - PAD, iy = py - PAD;

    uint2 t = make_uint2(0u, 0u);
    if ((unsigned)ix < IMG && (unsigned)iy < IMG) {
        const size_t o = (size_t)iy * IMG + ix;
        const __half2 lo = __floats2half2_rn(x[o],                 x[o + IMG * IMG]);
        const __half2 hi = __floats2half2_rn(x[o + 2 * IMG * IMG], x[o + 3 * IMG * IMG]);
        t.x = h22u(lo);
        t.y = h22u(hi);
    }
    if (px < PS && py < PS) ws[(size_t)py * PS + px] = t;          // N[py][px]
    tile[ty][tx] = t;
    __syncthreads();
    const int opx = blockIdx.y * 32 + tx;  // fast dim = original py
    const int opy = blockIdx.x * 32 + ty;  // slow dim = original px
    if (opx < PS && opy < PS)
        ws[(size_t)PSZ + (size_t)opy * PS + opx] = tile[tx][ty];   // T[u][v]=img[v][u]
}

// ---- main: grid (angle, ih*2+jh); 512 thr = 8 waves; wave = 16 j x 4 i-lanes ----
__global__ __launch_bounds__(512) void radon_main(const uint2* __restrict__ ws,
                                                  float4* __restrict__ proj_part) {
    const int a    = blockIdx.x;
    const int ih   = blockIdx.y >> 1;      // i-half: 0..1 (128 i's each)
    const int jh   = blockIdx.y & 1;       // j-half: 0..1 (128 j's each)
    const int lane = threadIdx.x & 63;
    const int wv   = threadIdx.x >> 6;     // wave 0..7 -> j-tile
    const int jj   = lane & 15;
    const int ii4  = lane >> 4;            // 0..3 i-subgroup
    const int j    = jh * 128 + wv * 16 + jj;

    const float ang = (float)a * 0.017453292519943295f;
    const float cs = cosf(ang);            // cos(-ang)
    const float sn = -sinf(ang);           // sin(-ang)

    const float xcj = -1.0f + (2.0f / 255.0f) * (float)j;
    const float fx0 = 127.5f * (xcj * cs + sn + 1.0f);
    const float dfx = -sn;
    const float fy0 = 127.5f * (xcj * sn - cs + 1.0f);
    const float dfy = cs;

    // layout so the lane-fast (j) coordinate strides the stored-row direction
    const bool swp = fabsf(sn) > fabsf(cs);
    const float rc0 = swp ? fx0 : fy0;  const float drow = swp ? dfx : dfy;
    const float cc0 = swp ? fy0 : fx0;  const float dcol = swp ? dfy : dfx;
    const uint2* __restrict__ base = ws + (swp ? PSZ : 0);

    // valid i-window (conservative; slop lands in the zero pad)
    float lo = 0.0f, hi = 255.0f;
    if (fabsf(drow) > 1e-5f) {
        const float t1 = (-1.5f - rc0) / drow, t2 = (256.5f - rc0) / drow;
        lo = fmaxf(lo, fminf(t1, t2));
        hi = fminf(hi, fmaxf(t1, t2));
    } else if (rc0 < -1.5f || rc0 > 256.5f) { lo = 1.0f; hi = 0.0f; }
    if (fabsf(dcol) > 1e-5f) {
        const float t1 = (-1.5f - cc0) / dcol, t2 = (256.5f - cc0) / dcol;
        lo = fmaxf(lo, fminf(t1, t2));
        hi = fminf(hi, fmaxf(t1, t2));
    } else if (cc0 < -1.5f || cc0 > 256.5f) { lo = 1.0f; hi = 0.0f; }

    const int ibase = ih * 128;
    int ilo_t = max((int)floorf(lo), ibase);
    int ihi_t = min((int)ceilf(hi), ibase + 127);
    ihi_t = min(ihi_t, 255);
    // thread's i-set: ibase + ii4 + 4k, k in [klo, khi]
    const int d0 = ilo_t - ibase - ii4;
    const int d1 = ihi_t - ibase - ii4;
    const int klo = max(0, (d0 + 3) >> 2);   // ceil-div, floor-shift ok for negatives
    const int khi = min(31, d1 >> 2);

    float4 sum = make_float4(0.f, 0.f, 0.f, 0.f);
    #pragma unroll 4
    for (int k = klo; k <= khi; ++k) {
        const int i = ibase + ii4 + (k << 2);
        const float rc = fmaf((float)i, drow, rc0);
        const float cc = fmaf((float)i, dcol, cc0);
        const float rf = floorf(rc);
        const float cf = floorf(cc);
        const float wr = rc - rf;
        const float wc = cc - cf;
        const int idx = (int)fmaf(rf, (float)PS, cf) + (PAD * PS + PAD);

        const uint4 tr = *reinterpret_cast<const uint4*>(base + idx);       // row r0: cols c0,c0+1
        const uint4 br = *reinterpret_cast<const uint4*>(base + idx + PS);  // row r0+1

        const __half2 wc2 = __float2half2_rn(wc);
        const __half2 wr2 = __float2half2_rn(wr);

        const __half2 v00a = u2h2(tr.x), v00b = u2h2(tr.y);
        const __half2 v01a = u2h2(tr.z), v01b = u2h2(tr.w);
        const __half2 v10a = u2h2(br.x), v10b = u2h2(br.y);
        const __half2 v11a = u2h2(br.z), v11b = u2h2(br.w);

        const __half2 topa = __hfma2(wc2, __hsub2(v01a, v00a), v00a);
        const __half2 topb = __hfma2(wc2, __hsub2(v01b, v00b), v00b);
        const __half2 bota = __hfma2(wc2, __hsub2(v11a, v10a), v10a);
        const __half2 botb = __hfma2(wc2, __hsub2(v11b, v10b), v10b);
        const __half2 ra = __hfma2(wr2, __hsub2(bota, topa), topa);
        const __half2 rb = __hfma2(wr2, __hsub2(botb, topb), topb);

        sum.x += __low2float(ra);
        sum.y += __high2float(ra);
        sum.z += __low2float(rb);
        sum.w += __high2float(rb);
    }

    // butterfly-reduce across the 4 i-subgroups (lanes jj, jj+16, jj+32, jj+48)
    sum.x += __shfl_xor(sum.x, 16, 64);
    sum.y += __shfl_xor(sum.y, 16, 64);
    sum.z += __shfl_xor(sum.z, 16, 64);
    sum.w += __shfl_xor(sum.w, 16, 64);
    sum.x += __shfl_xor(sum.x, 32, 64);
    sum.y += __shfl_xor(sum.y, 32, 64);
    sum.z += __shfl_xor(sum.z, 32, 64);
    sum.w += __shfl_xor(sum.w, 32, 64);

    if (ii4 == 0) {
        proj_part[(size_t)(a * 2 + ih) * IMG + j] = sum;
    }
}

// ---- detect: per angle, sum 2 i-halves, resample detectors, write 4 batches ----
__global__ __launch_bounds__(384) void detect_kernel(const float4* __restrict__ proj_part,
                                                     float* __restrict__ out) {
    const int a = blockIdx.x;
    const int t = threadIdx.x;
    __shared__ float4 proj[IMG];
    if (t < IMG) {
        const float4 p0 = proj_part[(size_t)(a * 2 + 0) * IMG + t];
        const float4 p1 = proj_part[(size_t)(a * 2 + 1) * IMG + t];
        proj[t] = make_float4(p0.x + p1.x, p0.y + p1.y, p0.z + p1.z, p0.w + p1.w);
    }
    __syncthreads();
    if (t < NDET) {
        const float pos = (float)t * (255.0f / 362.0f);
        const float fp = floorf(pos);
        const int p0 = (int)fp;
        const int p1 = min(p0 + 1, IMG - 1);
        const float w = pos - fp;
        const float4 lo = proj[p0], hi = proj[p1];
        const size_t o = (size_t)a * NDET + t;
        out[o]                   = fmaf(w, hi.x - lo.x, lo.x);
        out[o + 1 * NANG * NDET] = fmaf(w, hi.y - lo.y, lo.y);
        out[o + 2 * NANG * NDET] = fmaf(w, hi.z - lo.z, lo.z);
        out[o + 3 * NANG * NDET] = fmaf(w, hi.w - lo.w, lo.w);
    }
}

// ---- fallback (round-1 kernel) if ws is too small ----
__global__ __launch_bounds__(256) void radon_fallback(const float* __restrict__ x,
                                                      float* __restrict__ out) {
    const int blk = blockIdx.x;
    const int a = blk >> 2;
    const int b = blk & 3;
    const int j = threadIdx.x;
    const float* __restrict__ img = x + (size_t)b * (IMG * IMG);
    const float ang = (float)a * 0.017453292519943295f;
    const float cs = cosf(ang);
    const float sn = -sinf(ang);
    const float xcj = -1.0f + (2.0f / 255.0f) * (float)j;
    const float gx0 = xcj * cs;
    const float gy0 = xcj * sn;
    float sum = 0.0f;
    for (int i = 0; i < IMG; ++i) {
        const float yci = -1.0f + (2.0f / 255.0f) * (float)i;
        const float fx = (gx0 - yci * sn + 1.0f) * 127.5f;
        const float fy = (gy0 + yci * cs + 1.0f) * 127.5f;
        const float flx = floorf(fx), fly = floorf(fy);
        const int x0 = (int)flx, y0 = (int)fly;
        const float wx = fx - flx, wy = fy - fly;
        const bool vx0 = ((unsigned)x0 < IMG), vx1 = ((unsigned)(x0 + 1) < IMG);
        const bool vy0 = ((unsigned)y0 < IMG), vy1 = ((unsigned)(y0 + 1) < IMG);
        if (!((vx0 | vx1) & (vy0 | vy1))) continue;
        const int xc0 = min(max(x0, 0), IMG - 1), xc1 = min(max(x0 + 1, 0), IMG - 1);
        const int yc0 = min(max(y0, 0), IMG - 1), yc1 = min(max(y0 + 1, 0), IMG - 1);
        const float* r0 = img + yc0 * IMG;
        const float* r1 = img + yc1 * IMG;
        const float v00 = (vy0 && vx0) ? r0[xc0] : 0.0f;
        const float v01 = (vy0 && vx1) ? r0[xc1] : 0.0f;
        const float v10 = (vy1 && vx0) ? r1[xc0] : 0.0f;
        const float v11 = (vy1 && vx1) ? r1[xc1] : 0.0f;
        sum += (1.0f - wy) * ((1.0f - wx) * v00 + wx * v01)
             +         wy  * ((1.0f - wx) * v10 + wx * v11);
    }
    __shared__ float proj[IMG];
    proj[j] = sum;
    __syncthreads();
    for (int d = j; d < NDET; d += 256) {
        const float pos = (float)d * (255.0f / 362.0f);
        const float fp = floorf(pos);
        const int p0 = (int)fp;
        const int p1 = min(p0 + 1, IMG - 1);
        const float w = pos - fp;
        out[(size_t)b * (NANG * NDET) + a * NDET + d] = proj[p0] * (1.0f - w) + proj[p1] * w;
    }
}

extern "C" void kernel_launch(void* const* d_in, const int* in_sizes, int n_in,
                              void* d_out, int out_size, void* d_ws, size_t ws_size,
                              hipStream_t stream) {
    const float* x = (const float*)d_in[0];
    float* out = (float*)d_out;
    (void)in_sizes; (void)n_in; (void)out_size;

    if (ws_size >= WS_NEED) {
        uint2* tex = (uint2*)d_ws;
        float4* proj_part = (float4*)((char*)d_ws + TEX_BYTES);
        prep_kernel<<<dim3(9, 9), dim3(32, 32), 0, stream>>>(x, tex);
        radon_main<<<dim3(NANG, 4), dim3(512), 0, stream>>>(tex, proj_part);
        detect_kernel<<<dim3(NANG), dim3(384), 0, stream>>>(proj_part, out);
    } else {
        radon_fallback<<<dim3(NANG * 4), dim3(256), 0, stream>>>(x, out);
    }
}

// Round 7
// 31.060 us; speedup vs baseline: 7.8209x; 1.0117x over previous
//
#include <hip/hip_runtime.h>
#include <hip/hip_cooperative_groups.h>
#include <hip/hip_fp16.h>
#include <math.h>

namespace cg = cooperative_groups;

#define IMG   256
#define NANG  180
#define NDET  363
#define PAD   3
#define PS    264                    // padded stride (texels)
#define PSZ   (PS * PS)              // texels per layout
#define TEX_BYTES ((size_t)2 * PSZ * 8)          // 2 layouts of uint2 texels
#define PP_BYTES  ((size_t)NANG * 2 * IMG * 16)  // proj_part float4 (2 i-halves)
#define WS_NEED   (TEX_BYTES + PP_BYTES)

__device__ __forceinline__ __half2 u2h2(unsigned u) {
    return *reinterpret_cast<__half2*>(&u);
}
__device__ __forceinline__ unsigned h22u(__half2 h) {
    return *reinterpret_cast<unsigned*>(&h);
}

// ---------- shared device helpers ----------

// main-phase body: computes one (angle, ih, jh) quadrant. 512 threads.
__device__ __forceinline__ void main_phase(const uint2* __restrict__ ws,
                                           float4* __restrict__ proj_part,
                                           int a, int ih, int jh, int tid) {
    const int lane = tid & 63;
    const int wv   = tid >> 6;             // wave 0..7 -> j-tile
    const int jj   = lane & 15;
    const int ii4  = lane >> 4;            // 0..3 i-subgroup
    const int j    = jh * 128 + wv * 16 + jj;

    const float ang = (float)a * 0.017453292519943295f;
    const float cs = cosf(ang);            // cos(-ang)
    const float sn = -sinf(ang);           // sin(-ang)

    const float xcj = -1.0f + (2.0f / 255.0f) * (float)j;
    const float fx0 = 127.5f * (xcj * cs + sn + 1.0f);
    const float dfx = -sn;
    const float fy0 = 127.5f * (xcj * sn - cs + 1.0f);
    const float dfy = cs;

    // layout so the lane-fast (j) coordinate strides the stored-row direction
    const bool swp = fabsf(sn) > fabsf(cs);
    const float rc0 = swp ? fx0 : fy0;  const float drow = swp ? dfx : dfy;
    const float cc0 = swp ? fy0 : fx0;  const float dcol = swp ? dfy : dfx;
    const uint2* __restrict__ base = ws + (swp ? PSZ : 0);

    // valid i-window (conservative; slop lands in the zero pad)
    float lo = 0.0f, hi = 255.0f;
    if (fabsf(drow) > 1e-5f) {
        const float t1 = (-1.5f - rc0) / drow, t2 = (256.5f - rc0) / drow;
        lo = fmaxf(lo, fminf(t1, t2));
        hi = fminf(hi, fmaxf(t1, t2));
    } else if (rc0 < -1.5f || rc0 > 256.5f) { lo = 1.0f; hi = 0.0f; }
    if (fabsf(dcol) > 1e-5f) {
        const float t1 = (-1.5f - cc0) / dcol, t2 = (256.5f - cc0) / dcol;
        lo = fmaxf(lo, fminf(t1, t2));
        hi = fminf(hi, fmaxf(t1, t2));
    } else if (cc0 < -1.5f || cc0 > 256.5f) { lo = 1.0f; hi = 0.0f; }

    const int ibase = ih * 128;
    const int ilo_t = max((int)floorf(lo), ibase);
    int ihi_t = min((int)ceilf(hi), ibase + 127);
    ihi_t = min(ihi_t, 255);
    const int d0 = ilo_t - ibase - ii4;
    const int d1 = ihi_t - ibase - ii4;
    const int klo = max(0, (d0 + 3) >> 2);
    const int khi = min(31, d1 >> 2);

    float4 sum = make_float4(0.f, 0.f, 0.f, 0.f);
    #pragma unroll 4
    for (int k = klo; k <= khi; ++k) {
        const int i = ibase + ii4 + (k << 2);
        const float rc = fmaf((float)i, drow, rc0);
        const float cc = fmaf((float)i, dcol, cc0);
        const float rf = floorf(rc);
        const float cf = floorf(cc);
        const float wr = rc - rf;
        const float wc = cc - cf;
        const int idx = (int)fmaf(rf, (float)PS, cf) + (PAD * PS + PAD);

        const uint4 tr = *reinterpret_cast<const uint4*>(base + idx);
        const uint4 br = *reinterpret_cast<const uint4*>(base + idx + PS);

        const __half2 wc2 = __float2half2_rn(wc);
        const __half2 wr2 = __float2half2_rn(wr);

        const __half2 v00a = u2h2(tr.x), v00b = u2h2(tr.y);
        const __half2 v01a = u2h2(tr.z), v01b = u2h2(tr.w);
        const __half2 v10a = u2h2(br.x), v10b = u2h2(br.y);
        const __half2 v11a = u2h2(br.z), v11b = u2h2(br.w);

        const __half2 topa = __hfma2(wc2, __hsub2(v01a, v00a), v00a);
        const __half2 topb = __hfma2(wc2, __hsub2(v01b, v00b), v00b);
        const __half2 bota = __hfma2(wc2, __hsub2(v11a, v10a), v10a);
        const __half2 botb = __hfma2(wc2, __hsub2(v11b, v10b), v10b);
        const __half2 ra = __hfma2(wr2, __hsub2(bota, topa), topa);
        const __half2 rb = __hfma2(wr2, __hsub2(botb, topb), topb);

        sum.x += __low2float(ra);
        sum.y += __high2float(ra);
        sum.z += __low2float(rb);
        sum.w += __high2float(rb);
    }

    sum.x += __shfl_xor(sum.x, 16, 64);
    sum.y += __shfl_xor(sum.y, 16, 64);
    sum.z += __shfl_xor(sum.z, 16, 64);
    sum.w += __shfl_xor(sum.w, 16, 64);
    sum.x += __shfl_xor(sum.x, 32, 64);
    sum.y += __shfl_xor(sum.y, 32, 64);
    sum.z += __shfl_xor(sum.z, 32, 64);
    sum.w += __shfl_xor(sum.w, 32, 64);

    if (ii4 == 0) {
        proj_part[(size_t)(a * 2 + ih) * IMG + j] = sum;
    }
}

// ---------- fused cooperative kernel ----------
__global__ __launch_bounds__(512, 6) void radon_fused(const float* __restrict__ x,
                                                      uint2* __restrict__ tex,
                                                      float4* __restrict__ proj_part,
                                                      float* __restrict__ out) {
    cg::grid_group grid = cg::this_grid();
    const int bid = blockIdx.x;
    const int tid = threadIdx.x;

    __shared__ uint2 s_tile[16][33];
    __shared__ float4 s_proj[IMG];

    // ---- phase 1: prep (blocks 0..152 build the two texture layouts) ----
    if (bid < 9 * 17) {
        const int bx = bid % 9, by = bid / 9;       // 32-wide, 16-tall tiles
        const int tx = tid & 31, ty = tid >> 5;     // 32 x 16
        const int px = bx * 32 + tx;                // padded x
        const int py = by * 16 + ty;                // padded y
        const int ix = px - PAD, iy = py - PAD;

        uint2 t = make_uint2(0u, 0u);
        if ((unsigned)ix < IMG && (unsigned)iy < IMG) {
            const size_t o = (size_t)iy * IMG + ix;
            const __half2 lo = __floats2half2_rn(x[o],                 x[o + IMG * IMG]);
            const __half2 hi = __floats2half2_rn(x[o + 2 * IMG * IMG], x[o + 3 * IMG * IMG]);
            t.x = h22u(lo);
            t.y = h22u(hi);
        }
        if (px < PS && py < PS) tex[(size_t)py * PS + px] = t;     // N[py][px]
        s_tile[ty][tx] = t;
        __syncthreads();
        // transposed: T[u=px][v=py] = texel(py=v, px=u)
        const int u_local = tid >> 4;    // 0..31
        const int v_local = tid & 15;    // 0..15
        const int u = bx * 32 + u_local;
        const int v = by * 16 + v_local;
        if (u < PS && v < PS)
            tex[(size_t)PSZ + (size_t)u * PS + v] = s_tile[v_local][u_local];
    }

    grid.sync();

    // ---- phase 2: main (all 720 blocks; bid -> (a, ih, jh)) ----
    {
        const int a  = bid >> 2;
        const int ih = (bid >> 1) & 1;
        const int jh = bid & 1;
        main_phase(tex, proj_part, a, ih, jh, tid);
    }

    grid.sync();

    // ---- phase 3: detect (blocks 0..179, one per angle) ----
    if (bid < NANG) {
        const int a = bid;
        if (tid < IMG) {
            const float4 p0 = proj_part[(size_t)(a * 2 + 0) * IMG + tid];
            const float4 p1 = proj_part[(size_t)(a * 2 + 1) * IMG + tid];
            s_proj[tid] = make_float4(p0.x + p1.x, p0.y + p1.y, p0.z + p1.z, p0.w + p1.w);
        }
        __syncthreads();
        if (tid < NDET) {
            const float pos = (float)tid * (255.0f / 362.0f);
            const float fp = floorf(pos);
            const int p0 = (int)fp;
            const int p1 = min(p0 + 1, IMG - 1);
            const float w = pos - fp;
            const float4 lo = s_proj[p0], hi = s_proj[p1];
            const size_t o = (size_t)a * NDET + tid;
            out[o]                   = fmaf(w, hi.x - lo.x, lo.x);
            out[o + 1 * NANG * NDET] = fmaf(w, hi.y - lo.y, lo.y);
            out[o + 2 * NANG * NDET] = fmaf(w, hi.z - lo.z, lo.z);
            out[o + 3 * NANG * NDET] = fmaf(w, hi.w - lo.w, lo.w);
        }
    }
}

// ---------- classic 3-kernel path (fallback if cooperative capacity short) ----------
__global__ __launch_bounds__(1024) void prep_kernel(const float* __restrict__ x,
                                                    uint2* __restrict__ ws) {
    __shared__ uint2 tile[32][33];
    const int tx = threadIdx.x, ty = threadIdx.y;
    const int px = blockIdx.x * 32 + tx;
    const int py = blockIdx.y * 32 + ty;
    const int ix = px - PAD, iy = py - PAD;

    uint2 t = make_uint2(0u, 0u);
    if ((unsigned)ix < IMG && (unsigned)iy < IMG) {
        const size_t o = (size_t)iy * IMG + ix;
        const __half2 lo = __floats2half2_rn(x[o],                 x[o + IMG * IMG]);
        const __half2 hi = __floats2half2_rn(x[o + 2 * IMG * IMG], x[o + 3 * IMG * IMG]);
        t.x = h22u(lo);
        t.y = h22u(hi);
    }
    if (px < PS && py < PS) ws[(size_t)py * PS + px] = t;
    tile[ty][tx] = t;
    __syncthreads();
    const int opx = blockIdx.y * 32 + tx;
    const int opy = blockIdx.x * 32 + ty;
    if (opx < PS && opy < PS)
        ws[(size_t)PSZ + (size_t)opy * PS + opx] = tile[tx][ty];
}

__global__ __launch_bounds__(512) void radon_main(const uint2* __restrict__ ws,
                                                  float4* __restrict__ proj_part) {
    main_phase(ws, proj_part, blockIdx.x, blockIdx.y >> 1, blockIdx.y & 1, threadIdx.x);
}

__global__ __launch_bounds__(384) void detect_kernel(const float4* __restrict__ proj_part,
                                                     float* __restrict__ out) {
    const int a = blockIdx.x;
    const int t = threadIdx.x;
    __shared__ float4 proj[IMG];
    if (t < IMG) {
        const float4 p0 = proj_part[(size_t)(a * 2 + 0) * IMG + t];
        const float4 p1 = proj_part[(size_t)(a * 2 + 1) * IMG + t];
        proj[t] = make_float4(p0.x + p1.x, p0.y + p1.y, p0.z + p1.z, p0.w + p1.w);
    }
    __syncthreads();
    if (t < NDET) {
        const float pos = (float)t * (255.0f / 362.0f);
        const float fp = floorf(pos);
        const int p0 = (int)fp;
        const int p1 = min(p0 + 1, IMG - 1);
        const float w = pos - fp;
        const float4 lo = proj[p0], hi = proj[p1];
        const size_t o = (size_t)a * NDET + t;
        out[o]                   = fmaf(w, hi.x - lo.x, lo.x);
        out[o + 1 * NANG * NDET] = fmaf(w, hi.y - lo.y, lo.y);
        out[o + 2 * NANG * NDET] = fmaf(w, hi.z - lo.z, lo.z);
        out[o + 3 * NANG * NDET] = fmaf(w, hi.w - lo.w, lo.w);
    }
}

// ---- last-resort fallback (no workspace) ----
__global__ __launch_bounds__(256) void radon_fallback(const float* __restrict__ x,
                                                      float* __restrict__ out) {
    const int blk = blockIdx.x;
    const int a = blk >> 2;
    const int b = blk & 3;
    const int j = threadIdx.x;
    const float* __restrict__ img = x + (size_t)b * (IMG * IMG);
    const float ang = (float)a * 0.017453292519943295f;
    const float cs = cosf(ang);
    const float sn = -sinf(ang);
    const float xcj = -1.0f + (2.0f / 255.0f) * (float)j;
    const float gx0 = xcj * cs;
    const float gy0 = xcj * sn;
    float sum = 0.0f;
    for (int i = 0; i < IMG; ++i) {
        const float yci = -1.0f + (2.0f / 255.0f) * (float)i;
        const float fx = (gx0 - yci * sn + 1.0f) * 127.5f;
        const float fy = (gy0 + yci * cs + 1.0f) * 127.5f;
        const float flx = floorf(fx), fly = floorf(fy);
        const int x0 = (int)flx, y0 = (int)fly;
        const float wx = fx - flx, wy = fy - fly;
        const bool vx0 = ((unsigned)x0 < IMG), vx1 = ((unsigned)(x0 + 1) < IMG);
        const bool vy0 = ((unsigned)y0 < IMG), vy1 = ((unsigned)(y0 + 1) < IMG);
        if (!((vx0 | vx1) & (vy0 | vy1))) continue;
        const int xc0 = min(max(x0, 0), IMG - 1), xc1 = min(max(x0 + 1, 0), IMG - 1);
        const int yc0 = min(max(y0, 0), IMG - 1), yc1 = min(max(y0 + 1, 0), IMG - 1);
        const float* r0 = img + yc0 * IMG;
        const float* r1 = img + yc1 * IMG;
        const float v00 = (vy0 && vx0) ? r0[xc0] : 0.0f;
        const float v01 = (vy0 && vx1) ? r0[xc1] : 0.0f;
        const float v10 = (vy1 && vx0) ? r1[xc0] : 0.0f;
        const float v11 = (vy1 && vx1) ? r1[xc1] : 0.0f;
        sum += (1.0f - wy) * ((1.0f - wx) * v00 + wx * v01)
             +         wy  * ((1.0f - wx) * v10 + wx * v11);
    }
    __shared__ float proj[IMG];
    proj[j] = sum;
    __syncthreads();
    for (int d = j; d < NDET; d += 256) {
        const float pos = (float)d * (255.0f / 362.0f);
        const float fp = floorf(pos);
        const int p0 = (int)fp;
        const int p1 = min(p0 + 1, IMG - 1);
        const float w = pos - fp;
        out[(size_t)b * (NANG * NDET) + a * NDET + d] = proj[p0] * (1.0f - w) + proj[p1] * w;
    }
}

extern "C" void kernel_launch(void* const* d_in, const int* in_sizes, int n_in,
                              void* d_out, int out_size, void* d_ws, size_t ws_size,
                              hipStream_t stream) {
    const float* x = (const float*)d_in[0];
    float* out = (float*)d_out;
    (void)in_sizes; (void)n_in; (void)out_size;

    if (ws_size < WS_NEED) {
        radon_fallback<<<dim3(NANG * 4), dim3(256), 0, stream>>>(x, out);
        return;
    }

    uint2* tex = (uint2*)d_ws;
    float4* proj_part = (float4*)((char*)d_ws + TEX_BYTES);

    // host-side capacity check (pure computation; graph-capture safe)
    int blocksPerCU = 0;
    hipError_t occ_err = hipOccupancyMaxActiveBlocksPerMultiprocessor(
        &blocksPerCU, (const void*)radon_fused, 512, 0);

    if (occ_err == hipSuccess && blocksPerCU * 256 >= NANG * 4) {
        void* args[] = {(void*)&x, (void*)&tex, (void*)&proj_part, (void*)&out};
        hipError_t err = hipLaunchCooperativeKernel((const void*)radon_fused,
                                                    dim3(NANG * 4), dim3(512),
                                                    args, 0, stream);
        if (err == hipSuccess) return;
    }

    // classic 3-kernel path
    prep_kernel<<<dim3(9, 9), dim3(32, 32), 0, stream>>>(x, tex);
    radon_main<<<dim3(NANG, 4), dim3(512), 0, stream>>>(tex, proj_part);
    detect_kernel<<<dim3(NANG), dim3(384), 0, stream>>>(proj_part, out);
}